// Round 1
// 376.000 us; speedup vs baseline: 1.0062x; 1.0062x over previous
//
#include <hip/hip_runtime.h>

// out[b,i,o] = S[b,i,:]·W[o,:] + A[b,i]*bias[o]
//   S[b,i,d] = sum_j adj[b,i,j]*(text[b,j,d] + dep[b,j,i,d]),  A = sum_j adj
//
// Fused single-phase: 1024 blocks = one per (b,i); 4 blocks/CU = 16 waves/CU.
//   - dep stream nontemporal (zero reuse), 16 B/lane coalesced, j strided.
//   - text term from L2 (1 MB resident).
//   - LDS reduce 4 j-groups -> S[256], then W epilogue in the same block.
//   Removes: spS workspace round-trip (2 MB W + 2 MB R), second dispatch,
//   phase2's adj re-read. 16 waves/CU is ample MLP for the HBM stream
//   (need ~9 KB in flight/CU; unroll-4 x 1024 lanes/CU gives >>64 KB).

#define LL 256
#define DD 256
#define D4 64   // DD/4

// native clang vector type — __builtin_nontemporal_load needs this
typedef float float4n __attribute__((ext_vector_type(4)));

__global__ __launch_bounds__(256, 4) void tgc_fused(
    const float* __restrict__ text,     // [B,L,D]
    const float* __restrict__ adj,      // [B,L,L]
    const float* __restrict__ dep,      // [B,L,L,D]
    const float* __restrict__ W,        // [Do,Di]
    const float* __restrict__ bias,     // [Do]
    float* __restrict__ out)            // [B,L,Do]
{
    const int bi = blockIdx.x;          // (b,i)
    const int b  = bi >> 8;
    const int i  = bi & 255;
    const int t  = threadIdx.x;
    const int g  = t >> 6;              // wave = j-group 0..3
    const int l  = t & 63;              // d4 index

    __shared__ float  adjs[LL];
    __shared__ float4 red[4][64];
    __shared__ float4 sfin[64];
    __shared__ float  ared[4];

    const float av = adj[bi * LL + t];  // adj[b,i,t]
    adjs[t] = av;
    __syncthreads();

    const float4n* __restrict__ dep4  = (const float4n*)dep;
    const float4*  __restrict__ text4 = (const float4*)text;

    float4 acc = make_float4(0.f, 0.f, 0.f, 0.f);

    // dep stream: j = 4*jj + g, jj = 0..63 (nontemporal: zero reuse)
    {
        const float4n* dp = dep4 + (((size_t)(b * LL + g) * LL + i) * D4 + l);
        const size_t   JS = (size_t)4 * LL * D4;
        #pragma unroll 4
        for (int jj = 0; jj < 64; ++jj) {
            const float   a = adjs[(jj << 2) + g];
            const float4n d = __builtin_nontemporal_load(dp);
            acc.x += a * d.x;
            acc.y += a * d.y;
            acc.z += a * d.z;
            acc.w += a * d.w;
            dp += JS;
        }
    }
    // text term for the same j's (L2-resident, 1 MB total)
    {
        const float4* tp = text4 + ((size_t)(b * LL + g) * D4 + l);
        const size_t  TS = (size_t)4 * D4;
        #pragma unroll 4
        for (int jj = 0; jj < 64; ++jj) {
            const float  a  = adjs[(jj << 2) + g];
            const float4 tv = *tp;
            acc.x += a * tv.x;
            acc.y += a * tv.y;
            acc.z += a * tv.z;
            acc.w += a * tv.w;
            tp += TS;
        }
    }

    // A = sum_j adj[b,i,j] — wave reduce (each wave owns 64 consecutive j)
    float avs = av;
    #pragma unroll
    for (int off = 32; off > 0; off >>= 1) avs += __shfl_down(avs, off);
    if (l == 0) ared[g] = avs;

    red[g][l] = acc;
    __syncthreads();
    if (g == 0) {
        const float4 r0 = red[0][l], r1 = red[1][l], r2 = red[2][l], r3 = red[3][l];
        sfin[l] = make_float4(r0.x + r1.x + r2.x + r3.x,
                              r0.y + r1.y + r2.y + r3.y,
                              r0.z + r1.z + r2.z + r3.z,
                              r0.w + r1.w + r2.w + r3.w);
    }
    __syncthreads();

    const float A = ared[0] + ared[1] + ared[2] + ared[3];

    // thread t = output column o; W row L2-resident (256 KB)
    const float4* W4 = (const float4*)W;
    float oacc = 0.f;
    #pragma unroll 8
    for (int d4 = 0; d4 < D4; ++d4) {
        const float4 s  = sfin[d4];
        const float4 wv = W4[t * D4 + d4];
        oacc += s.x * wv.x + s.y * wv.y + s.z * wv.z + s.w * wv.w;
    }
    out[bi * DD + t] = oacc + A * bias[t];
}

extern "C" void kernel_launch(void* const* d_in, const int* in_sizes, int n_in,
                              void* d_out, int out_size, void* d_ws, size_t ws_size,
                              hipStream_t stream) {
    const float* text = (const float*)d_in[0];
    const float* adj  = (const float*)d_in[1];
    const float* dep  = (const float*)d_in[2];
    const float* W    = (const float*)d_in[3];
    const float* bias = (const float*)d_in[4];
    float* out = (float*)d_out;

    tgc_fused<<<dim3(1024), dim3(256), 0, stream>>>(text, adj, dep, W, bias, out);
}